// Round 12
// baseline (137.793 us; speedup 1.0000x reference)
//
#include <hip/hip_runtime.h>

#define B_N 4096
#define F_N 1024
#define H_N 4
#define D_N 256
#define BF_ELEMS (B_N * F_N)   // 4194304

typedef unsigned short u16;
typedef __bf16 bf16x8 __attribute__((ext_vector_type(8)));
typedef float f32x4 __attribute__((ext_vector_type(4)));
typedef u16 u16x4 __attribute__((ext_vector_type(4)));
typedef u16 u16x8 __attribute__((ext_vector_type(8)));

__device__ __forceinline__ u16 f2bf(float v) {
    union { float f; unsigned u; } x; x.f = v;
    unsigned r = x.u + 0x7fffu + ((x.u >> 16) & 1u);
    return (u16)(r >> 16);
}

__device__ __forceinline__ float bf2f(u16 v) {
    union { unsigned u; float f; } x; x.u = ((unsigned)v) << 16;
    return x.f;
}

// Fused prep: blocks 0..4095 = conv step + state shift + flag + bf16 casts;
// blocks 4096..6143 = weight f32->bf16 re-layout to wt2[mat][ks][e][k%32]
// (16 KB contiguous per (mat, ks) -> stageable B-tiles in kfused).
__global__ __launch_bounds__(256) void kprep(
    const float* __restrict__ inputs, const float* __restrict__ cs,
    const float* __restrict__ ck, const float* __restrict__ cb,
    const float* __restrict__ h, const float* __restrict__ n,
    const float* W0, const float* W1, const float* W2, const float* W3,
    const float* W4, const float* W5, const float* W6, const float* W7,
    float* __restrict__ ncs_out, u16* __restrict__ convact,
    u16* __restrict__ hbf, u16* __restrict__ inbf,
    u16* __restrict__ wt, int* __restrict__ flag) {
    __shared__ float tile[32][33];
    int bid = blockIdx.x;
    int t = threadIdx.x;
    if (bid < 4096) {
        int idx = bid * 256 + t;
        int flat = idx << 2;
        int b = flat >> 10;
        int f = flat & 1023;
        const f32x4 x  = *(const f32x4*)(inputs + flat);
        const f32x4 c1 = *(const f32x4*)(cs + b * 4096 + 1024 + f);
        const f32x4 c2 = *(const f32x4*)(cs + b * 4096 + 2048 + f);
        const f32x4 c3 = *(const f32x4*)(cs + b * 4096 + 3072 + f);
        const f32x4 k0 = *(const f32x4*)(ck + f);
        const f32x4 k1 = *(const f32x4*)(ck + 1024 + f);
        const f32x4 k2 = *(const f32x4*)(ck + 2048 + f);
        const f32x4 k3 = *(const f32x4*)(ck + 3072 + f);
        const f32x4 bias = *(const f32x4*)(cb + f);
        const f32x4 h4 = *(const f32x4*)(h + flat);
        const f32x4 nv = *(const f32x4*)(n + flat);

        // any(n != 0): benign race, only 1 ever stored (plain store per wave)
        bool any = (nv[0] != 0.f) || (nv[1] != 0.f) || (nv[2] != 0.f) || (nv[3] != 0.f);
        unsigned long long msk = __ballot(any);
        if (msk && (t & 63) == 0) *flag = 1;

        u16x4 ca, hb, ib;
        #pragma unroll
        for (int q = 0; q < 4; ++q) {
            float v = c1[q] * k0[q] + c2[q] * k1[q] + c3[q] * k2[q] + x[q] * k3[q] + bias[q];
            float a = v / (1.f + expf(-v));   // silu
            ca[q] = f2bf(a);
            hb[q] = f2bf(h4[q]);
            ib[q] = f2bf(x[q]);
        }
        *(u16x4*)(convact + flat) = ca;
        *(u16x4*)(hbf + flat) = hb;
        *(u16x4*)(inbf + flat) = ib;

        float* ob = ncs_out + b * 4096 + f;
        *(f32x4*)(ob)        = c1;
        *(f32x4*)(ob + 1024) = c2;
        *(f32x4*)(ob + 2048) = c3;
        *(f32x4*)(ob + 3072) = x;
    } else {
        int wb = bid - 4096;          // 0..2047 = 64 tiles x 4 heads x 8 mats
        int gx = wb & 63;
        int hd = (wb >> 6) & 3;
        int mat = wb >> 8;
        const float* tab[8] = {W0, W1, W2, W3, W4, W5, W6, W7};
        const float* src = tab[mat] + hd * 65536;
        u16* dst = wt + (mat * 4 + hd) * 65536;
        int tx = t & 31, ty = t >> 5;
        int bx = (gx & 7) * 32;   // e tile
        int by = (gx >> 3) * 32;  // k tile
        #pragma unroll
        for (int r = 0; r < 4; ++r)
            tile[ty + r * 8][tx] = src[(by + ty + r * 8) * 256 + bx + tx];
        __syncthreads();
        // wt2[ks = k/32][e][k%32]: e = bx+ty+r*8, k = by+tx
        #pragma unroll
        for (int r = 0; r < 4; ++r)
            dst[(by >> 5) * 8192 + (bx + ty + r * 8) * 32 + tx] = f2bf(tile[tx][ty + r * 8]);
    }
}

// Fused GEMM + pointwise + per-head LayerNorm, LDS-staged B (R12).
// Block = 64 rows x one head x all 4 gates. 1024 thr = 16 waves (gate g,
// quarter q), wave tile 64x64, acc[4][4] = 64 VGPR (fits the 128-VGPR cap a
// 16-wave block forces). BK=32 double-buffer: per K-step stage B = 4 mats x
// 16 KB (contiguous in wt2) + A slices via global_load_lds, swizzle
// slot = granule ^ (row&3) on BOTH sides (validated R10). Stage-next ->
// compute -> barrier (R8 pattern). Epilogue: acc -> 128 KB LDS gbuf ->
// pointwise + LN (16-lane groups) -> direct writes of all 5 outputs.
// gates16 round-trip and kpoint launch eliminated.
// grid: (64 mtiles, 4 heads) = 256 blocks = 1/CU, one pass, no tail.
__global__ __launch_bounds__(1024) void kfused(
    const u16* __restrict__ convact, const u16* __restrict__ inbf,
    const u16* __restrict__ hbf, const u16* __restrict__ wt2,
    const float* __restrict__ bgi, const float* __restrict__ bgf,
    const float* __restrict__ bgz, const float* __restrict__ bgo,
    const float* __restrict__ cin, const float* __restrict__ nin,
    const float* __restrict__ min, const float* __restrict__ ln_scale,
    const int* __restrict__ flagp, float* __restrict__ out) {
    // dbuf: 2 x { A[2][64][32] @ +0 (4096 u16), B[4][256][32] @ +4096 (32768 u16) }
    // = 2 x 36864 u16 = 144 KB. Epilogue gbuf[64][1024] = 65536 u16 reuses it.
    __shared__ __align__(16) u16 smem[73728];

    int t = threadIdx.x;
    int mtile = blockIdx.x;
    int hd = blockIdx.y;
    int row0 = mtile * 64;

    int srow = t >> 2;                   // B stage row 0..255
    int sgl = (t & 3) ^ (srow & 3);      // pre-swizzled source granule

    #define GLDS(src, dstoff)                                                     \
        __builtin_amdgcn_global_load_lds(                                         \
            (const __attribute__((address_space(1))) void*)(src),                 \
            (__attribute__((address_space(3))) void*)(&smem[dstoff]), 16, 0, 0)

    // B: 4 matrices (matoff + 0..3) at K-chunk ks -> dbase+4096 + rd*8192
    #define STAGE_B(dbase, matoff, ks) do {                                       \
        _Pragma("unroll")                                                         \
        for (int rd = 0; rd < 4; ++rd)                                            \
            GLDS(wt2 + (size_t)(((matoff) + rd) * 4 + hd) * 65536 + (ks) * 8192   \
                     + srow * 32 + sgl * 8,                                       \
                 (dbase) + 4096 + rd * 8192 + t * 8);                             \
    } while (0)

    // A (x-half): conv -> slot0, inputs -> slot1 (threads 0..511)
    #define STAGE_A0(dbase, ks) do {                                              \
        if (t < 512) {                                                            \
            const u16* asrc = (t < 256) ? convact : inbf;                         \
            int tt = t & 255;                                                     \
            int rr = tt >> 2;                                                     \
            int gg = (tt & 3) ^ (rr & 3);                                         \
            GLDS(asrc + (size_t)(row0 + rr) * 1024 + hd * 256 + (ks) * 32 + gg * 8, \
                 (dbase) + (t < 256 ? 0 : 2048) + tt * 8);                        \
        }                                                                         \
    } while (0)

    // A (h-half): hbf -> slot0 (threads 0..255)
    #define STAGE_A1(dbase, ks) do {                                              \
        if (t < 256) {                                                            \
            int rr = t >> 2;                                                      \
            int gg = (t & 3) ^ (rr & 3);                                          \
            GLDS(hbf + (size_t)(row0 + rr) * 1024 + hd * 256 + (ks) * 32 + gg * 8, \
                 (dbase) + t * 8);                                                \
        }                                                                         \
    } while (0)

    int lane = t & 63, lr = lane & 15, lk = lane >> 4;
    int w = t >> 6;
    int g = w >> 2;        // gate 0..3
    int q = w & 3;         // 64-col quarter within the gate's 256 cols
    int gl = lk ^ (lr & 3);   // swizzled read granule (rows are 16-multiples + lr)

    f32x4 acc[4][4];
    #pragma unroll
    for (int i = 0; i < 4; ++i)
        #pragma unroll
        for (int j = 0; j < 4; ++j)
            acc[i][j] = (f32x4){0.f, 0.f, 0.f, 0.f};

    #define COMPUTE(dbase, abase) do {                                            \
        bf16x8 a[4], bb[4];                                                       \
        _Pragma("unroll")                                                         \
        for (int mi = 0; mi < 4; ++mi)                                            \
            a[mi] = *(const bf16x8*)&smem[(abase) + (mi * 16 + lr) * 32 + gl * 8]; \
        _Pragma("unroll")                                                         \
        for (int ni = 0; ni < 4; ++ni)                                            \
            bb[ni] = *(const bf16x8*)&smem[(dbase) + 4096 + g * 8192              \
                                           + (q * 64 + ni * 16 + lr) * 32 + gl * 8]; \
        _Pragma("unroll")                                                         \
        for (int mi = 0; mi < 4; ++mi)                                            \
            _Pragma("unroll")                                                     \
            for (int ni = 0; ni < 4; ++ni)                                        \
                acc[mi][ni] = __builtin_amdgcn_mfma_f32_16x16x32_bf16(            \
                    a[mi], bb[ni], acc[mi][ni], 0, 0, 0);                         \
    } while (0)

    // prologue
    STAGE_B(0, 0, 0);
    STAGE_A0(0, 0);
    __syncthreads();

    // K first half: x-side (W mats 0..3); i,f read conv slot, z,o read inputs slot
    #pragma unroll 2
    for (int kt = 0; kt < 8; ++kt) {
        int cb = (kt & 1) ? 36864 : 0;
        int nb = (kt & 1) ? 0 : 36864;
        if (kt < 7) { STAGE_B(nb, 0, kt + 1); STAGE_A0(nb, kt + 1); }
        else        { STAGE_B(nb, 4, 0);      STAGE_A1(nb, 0); }
        int abase = cb + (g < 2 ? 0 : 2048);
        COMPUTE(cb, abase);
        __syncthreads();
    }
    // K second half: h-side (R mats 4..7); all gates read h slot
    #pragma unroll 2
    for (int kt = 0; kt < 8; ++kt) {
        int cb = (kt & 1) ? 36864 : 0;
        int nb = (kt & 1) ? 0 : 36864;
        if (kt < 7) { STAGE_B(nb, 4, kt + 1); STAGE_A1(nb, kt + 1); }
        COMPUTE(cb, cb);
        __syncthreads();
    }

    // ---- epilogue: acc (+bias) -> gbuf[64][1024] bf16
    {
        const float* bt = (g == 0 ? bgi : g == 1 ? bgf : g == 2 ? bgz : bgo)
                          + hd * 256 + q * 64;
        #pragma unroll
        for (int ni = 0; ni < 4; ++ni) {
            float bv = bt[ni * 16 + lr];
            int col = g * 256 + q * 64 + ni * 16 + lr;
            #pragma unroll
            for (int mi = 0; mi < 4; ++mi)
                #pragma unroll
                for (int r = 0; r < 4; ++r)
                    smem[(mi * 16 + lk * 4 + r) * 1024 + col] = f2bf(acc[mi][ni][r] + bv);
        }
    }
    __syncthreads();

    // ---- pointwise + LN: thread -> (row = t>>4, 16 feats at c0 = (t&15)*16)
    {
        int prow = t >> 4;
        int c0 = (t & 15) * 16;
        size_t idx = (size_t)(row0 + prow) * 1024 + hd * 256 + c0;
        int flag = *flagp;

        float cn[16], nn[16], mn[16], hn[16];
        float s = 0.f, ss = 0.f;
        #pragma unroll
        for (int e8 = 0; e8 < 2; ++e8) {
            u16x8 iv = *(const u16x8*)&smem[prow * 1024 + c0 + e8 * 8];
            u16x8 fv = *(const u16x8*)&smem[prow * 1024 + 256 + c0 + e8 * 8];
            u16x8 zv = *(const u16x8*)&smem[prow * 1024 + 512 + c0 + e8 * 8];
            u16x8 ov = *(const u16x8*)&smem[prow * 1024 + 768 + c0 + e8 * 8];
            #pragma unroll
            for (int j = 0; j < 8; ++j) {
                int e = e8 * 8 + j;
                float I = bf2f(iv[j]);
                float Fg = bf2f(fv[j]);
                float Z = bf2f(zv[j]);
                float O = bf2f(ov[j]);
                float cvq = cin[idx + e];
                float nvq = nin[idx + e];
                float mvq = min[idx + e];
                float og = 1.f / (1.f + expf(-O));
                float lf = (Fg >= 0.f) ? -log1pf(expf(-Fg)) : (Fg - log1pf(expf(Fg)));
                float mnew = flag ? fmaxf(lf + mvq, I) : I;
                float ip = fminf(expf(I - mnew), 1.f);
                float fp = fminf(expf(lf + mvq - mnew), 1.f);
                float cnew = fp * cvq + ip * tanhf(Z);
                float nnew = fp * nvq + ip;
                float hnew = og * (cnew / fmaxf(nnew, 1e-6f));
                cn[e] = cnew; nn[e] = nnew; mn[e] = mnew; hn[e] = hnew;
                s += hnew; ss += hnew * hnew;
            }
        }
        // LN over the 16 lanes of this row-group (each holds 16 of 256 feats)
        #pragma unroll
        for (int off = 8; off >= 1; off >>= 1) {
            s  += __shfl_xor(s, off, 16);
            ss += __shfl_xor(ss, off, 16);
        }
        float mu = s * (1.f / 256.f);
        float var = ss * (1.f / 256.f) - mu * mu;
        float rs = rsqrtf(var + 1e-6f);

        #pragma unroll
        for (int v4 = 0; v4 < 4; ++v4) {
            f32x4 o4, c4, n4, m4, h4;
            #pragma unroll
            for (int j = 0; j < 4; ++j) {
                int e = v4 * 4 + j;
                float sc = ln_scale[hd * 256 + c0 + e];
                o4[j] = (hn[e] - mu) * rs * sc;
                c4[j] = cn[e]; n4[j] = nn[e]; m4[j] = mn[e]; h4[j] = hn[e];
            }
            *(f32x4*)(out + idx + v4 * 4) = o4;
            *(f32x4*)(out + (size_t)BF_ELEMS + idx + v4 * 4) = c4;
            *(f32x4*)(out + 2 * (size_t)BF_ELEMS + idx + v4 * 4) = n4;
            *(f32x4*)(out + 3 * (size_t)BF_ELEMS + idx + v4 * 4) = m4;
            *(f32x4*)(out + 4 * (size_t)BF_ELEMS + idx + v4 * 4) = h4;
        }
    }
    #undef COMPUTE
    #undef STAGE_A1
    #undef STAGE_A0
    #undef STAGE_B
    #undef GLDS
}

extern "C" void kernel_launch(void* const* d_in, const int* in_sizes, int n_in,
                              void* d_out, int out_size, void* d_ws, size_t ws_size,
                              hipStream_t stream) {
    const float* inputs = (const float*)d_in[0];
    const float* c = (const float*)d_in[1];
    const float* n = (const float*)d_in[2];
    const float* m = (const float*)d_in[3];
    const float* h = (const float*)d_in[4];
    const float* conv_state = (const float*)d_in[5];
    const float* conv_kernel = (const float*)d_in[6];
    const float* conv_bias = (const float*)d_in[7];
    const float* W[8];
    for (int i = 0; i < 8; ++i) W[i] = (const float*)d_in[8 + i];
    const float* bgi = (const float*)d_in[16];
    const float* bgf = (const float*)d_in[17];
    const float* bgz = (const float*)d_in[18];
    const float* bgo = (const float*)d_in[19];
    const float* ln_scale = (const float*)d_in[20];
    float* out = (float*)d_out;

    char* ws = (char*)d_ws;
    int* flag = (int*)ws;
    u16* convact = (u16*)(ws + 256);
    u16* hbf = convact + BF_ELEMS;
    u16* inbf = hbf + BF_ELEMS;
    u16* wt2 = inbf + BF_ELEMS;                      // 8*4*65536 bf16

    hipMemsetAsync(flag, 0, 4, stream);
    kprep<<<6144, 256, 0, stream>>>(inputs, conv_state, conv_kernel, conv_bias, h, n,
                                    W[0], W[1], W[2], W[3], W[4], W[5], W[6], W[7],
                                    out + 5 * (size_t)BF_ELEMS, convact, hbf, inbf, wt2, flag);
    kfused<<<dim3(64, 4), 1024, 0, stream>>>(convact, inbf, hbf, wt2,
                                             bgi, bgf, bgz, bgo,
                                             c, n, m, ln_scale, flag, out);
}

// Round 13
// 115.884 us; speedup vs baseline: 1.1891x; 1.1891x over previous
//
#include <hip/hip_runtime.h>

#define B_N 4096
#define F_N 1024
#define H_N 4
#define D_N 256
#define BF_ELEMS (B_N * F_N)   // 4194304

typedef unsigned short u16;
typedef __bf16 bf16x8 __attribute__((ext_vector_type(8)));
typedef float f32x4 __attribute__((ext_vector_type(4)));
typedef u16 u16x4 __attribute__((ext_vector_type(4)));

__device__ __forceinline__ u16 f2bf(float v) {
    union { float f; unsigned u; } x; x.f = v;
    unsigned r = x.u + 0x7fffu + ((x.u >> 16) & 1u);
    return (u16)(r >> 16);
}

__device__ __forceinline__ float bf2f(u16 v) {
    union { unsigned u; float f; } x; x.u = ((unsigned)v) << 16;
    return x.f;
}

// Fused prep: blocks 0..4095 = conv step + state shift + flag + bf16 casts;
// blocks 4096..6143 = weight f32->bf16 transpose [k][e] -> [e][k].
// At its HBM floor (~220 MB ~= 35 us).
__global__ __launch_bounds__(256) void kprep(
    const float* __restrict__ inputs, const float* __restrict__ cs,
    const float* __restrict__ ck, const float* __restrict__ cb,
    const float* __restrict__ h, const float* __restrict__ n,
    const float* W0, const float* W1, const float* W2, const float* W3,
    const float* W4, const float* W5, const float* W6, const float* W7,
    float* __restrict__ ncs_out, u16* __restrict__ convact,
    u16* __restrict__ hbf, u16* __restrict__ inbf,
    u16* __restrict__ wt, int* __restrict__ flag) {
    __shared__ float tile[32][33];
    int bid = blockIdx.x;
    int t = threadIdx.x;
    if (bid < 4096) {
        int idx = bid * 256 + t;
        int flat = idx << 2;
        int b = flat >> 10;
        int f = flat & 1023;
        const f32x4 x  = *(const f32x4*)(inputs + flat);
        const f32x4 c1 = *(const f32x4*)(cs + b * 4096 + 1024 + f);
        const f32x4 c2 = *(const f32x4*)(cs + b * 4096 + 2048 + f);
        const f32x4 c3 = *(const f32x4*)(cs + b * 4096 + 3072 + f);
        const f32x4 k0 = *(const f32x4*)(ck + f);
        const f32x4 k1 = *(const f32x4*)(ck + 1024 + f);
        const f32x4 k2 = *(const f32x4*)(ck + 2048 + f);
        const f32x4 k3 = *(const f32x4*)(ck + 3072 + f);
        const f32x4 bias = *(const f32x4*)(cb + f);
        const f32x4 h4 = *(const f32x4*)(h + flat);
        const f32x4 nv = *(const f32x4*)(n + flat);

        // any(n != 0): benign race, only 1 ever stored (plain store per wave)
        bool any = (nv[0] != 0.f) || (nv[1] != 0.f) || (nv[2] != 0.f) || (nv[3] != 0.f);
        unsigned long long msk = __ballot(any);
        if (msk && (t & 63) == 0) *flag = 1;

        u16x4 ca, hb, ib;
        #pragma unroll
        for (int q = 0; q < 4; ++q) {
            float v = c1[q] * k0[q] + c2[q] * k1[q] + c3[q] * k2[q] + x[q] * k3[q] + bias[q];
            float a = v / (1.f + expf(-v));   // silu
            ca[q] = f2bf(a);
            hb[q] = f2bf(h4[q]);
            ib[q] = f2bf(x[q]);
        }
        *(u16x4*)(convact + flat) = ca;
        *(u16x4*)(hbf + flat) = hb;
        *(u16x4*)(inbf + flat) = ib;

        float* ob = ncs_out + b * 4096 + f;
        *(f32x4*)(ob)        = c1;
        *(f32x4*)(ob + 1024) = c2;
        *(f32x4*)(ob + 2048) = c3;
        *(f32x4*)(ob + 3072) = x;
    } else {
        int wb = bid - 4096;          // 0..2047 = 64 tiles x 4 heads x 8 mats
        int gx = wb & 63;
        int hd = (wb >> 6) & 3;
        int mat = wb >> 8;
        const float* tab[8] = {W0, W1, W2, W3, W4, W5, W6, W7};
        const float* src = tab[mat] + hd * 65536;
        u16* dst = wt + (mat * 4 + hd) * 65536;
        int tx = t & 31, ty = t >> 5;
        int bx = (gx & 7) * 32;   // e tile
        int by = (gx >> 3) * 32;  // k tile
        #pragma unroll
        for (int r = 0; r < 4; ++r)
            tile[ty + r * 8][tx] = src[(by + ty + r * 8) * 256 + bx + tx];
        __syncthreads();
        #pragma unroll
        for (int r = 0; r < 4; ++r)
            dst[(bx + ty + r * 8) * 256 + by + tx] = f2bf(tile[tx][ty + r * 8]);
    }
}

// gates16[g][b][hd*256+e] = bf16( x_g . W_g + h . R_g + b_g )
// R13 = R8 base (128x128 tile, BK=64, dbuf, both-sides swizzle, 4 waves 2x2,
// acc 4x4, no VGPR cap) with ONE change: the K-loop's __syncthreads (which
// carries an implicit s_waitcnt vmcnt(0) FULL DRAIN of the prefetch) is
// replaced by the counted-vmcnt two-barrier scheme (T4): prefetch stays in
// flight across the barrier; each wave passing the barrier proves its own
// current-tile loads landed (vmcnt(8) = leave exactly the next tile's 8
// loads/thread outstanding), so all-waves-past-barrier => tile complete.
__global__ __launch_bounds__(256) void kgemm(
    const u16* __restrict__ convact, const u16* __restrict__ inbf,
    const u16* __restrict__ hbf, const u16* __restrict__ wt,
    const float* __restrict__ bgi, const float* __restrict__ bgf,
    const float* __restrict__ bgz, const float* __restrict__ bgo,
    u16* __restrict__ gates16) {
    __shared__ u16 ldsA[2][128 * 64];   // 32 KB
    __shared__ u16 ldsB[2][128 * 64];   // 32 KB

    int t = threadIdx.x;
    int mtile = blockIdx.x;
    int ct = blockIdx.y;
    int gsel = ct >> 3;               // 0=i,1=f,2=z,3=o
    int etile = ct & 7;
    int hd = etile >> 1;
    int e0 = (etile & 1) * 128;       // within head
    int row0 = mtile * 128;

    const u16* a0 = (gsel >= 2 ? inbf : convact) + row0 * 1024 + hd * 256;
    const u16* a1 = hbf + row0 * 1024 + hd * 256;
    const u16* b0 = wt + (gsel * 4 + hd) * 65536 + e0 * 256;         // W part
    const u16* b1 = wt + ((gsel + 4) * 4 + hd) * 65536 + e0 * 256;   // R part
    const float* bias = (gsel == 0 ? bgi : gsel == 1 ? bgf : gsel == 2 ? bgz : bgo)
                        + hd * 256 + e0;

    f32x4 acc[4][4];
    #pragma unroll
    for (int i = 0; i < 4; ++i)
        #pragma unroll
        for (int j = 0; j < 4; ++j)
            acc[i][j] = (f32x4){0.f, 0.f, 0.f, 0.f};

    int lane = t & 63;
    int lr = lane & 15, lk = lane >> 4;
    int w = t >> 6;
    int wm = w >> 1, wn = w & 1;
    int wbase = t & ~63;                       // wave-uniform granule base
    int srow = t >> 3;                         // staging row (0..31), +s*32
    int gsw = (t & 7) ^ ((t >> 3) & 7);        // swizzled source granule

    // 8 global_load_lds per thread per tile (4 A rounds + 4 B rounds).
    #define STAGE_TILE(buf, kt) do {                                              \
        int kb = (kt) * 64;                                                       \
        const u16* ap = (kb < 256) ? (a0 + kb) : (a1 + (kb - 256));               \
        const u16* bp = (kb < 256) ? (b0 + kb) : (b1 + (kb - 256));               \
        _Pragma("unroll")                                                         \
        for (int s = 0; s < 4; ++s) {                                             \
            int row = srow + s * 32;                                              \
            __builtin_amdgcn_global_load_lds(                                     \
                (const __attribute__((address_space(1))) void*)(ap + row * 1024 + gsw * 8), \
                (__attribute__((address_space(3))) void*)(&ldsA[buf][(s * 256 + wbase) * 8]), \
                16, 0, 0);                                                        \
        }                                                                         \
        _Pragma("unroll")                                                         \
        for (int s = 0; s < 4; ++s) {                                             \
            int row = srow + s * 32;                                              \
            __builtin_amdgcn_global_load_lds(                                     \
                (const __attribute__((address_space(1))) void*)(bp + row * 256 + gsw * 8), \
                (__attribute__((address_space(3))) void*)(&ldsB[buf][(s * 256 + wbase) * 8]), \
                16, 0, 0);                                                        \
        }                                                                         \
    } while (0)

    STAGE_TILE(0, 0);

    for (int kt = 0; kt < 8; ++kt) {
        int buf = kt & 1;
        if (kt < 7) {
            STAGE_TILE(buf ^ 1, kt + 1);
            // leave next tile's 8 loads in flight; drain current tile's 8
            asm volatile("s_waitcnt vmcnt(8)" ::: "memory");
        } else {
            asm volatile("s_waitcnt vmcnt(0)" ::: "memory");
        }
        __builtin_amdgcn_s_barrier();        // all waves: current tile in LDS
        __builtin_amdgcn_sched_barrier(0);   // pin: no ds_read hoisted above

        #pragma unroll
        for (int kk = 0; kk < 2; ++kk) {
            bf16x8 a[4], bb[4];
            #pragma unroll
            for (int mi = 0; mi < 4; ++mi) {
                int row = wm * 64 + mi * 16 + lr;
                a[mi] = *(const bf16x8*)&ldsA[buf][row * 64 + (((kk * 4 + lk) ^ (row & 7)) * 8)];
            }
            #pragma unroll
            for (int ni = 0; ni < 4; ++ni) {
                int row = wn * 64 + ni * 16 + lr;
                bb[ni] = *(const bf16x8*)&ldsB[buf][row * 64 + (((kk * 4 + lk) ^ (row & 7)) * 8)];
            }
            #pragma unroll
            for (int mi = 0; mi < 4; ++mi)
                #pragma unroll
                for (int ni = 0; ni < 4; ++ni)
                    acc[mi][ni] = __builtin_amdgcn_mfma_f32_16x16x32_bf16(a[mi], bb[ni], acc[mi][ni], 0, 0, 0);
        }

        __builtin_amdgcn_s_barrier();        // all waves done reading buf
        __builtin_amdgcn_sched_barrier(0);   // pin: next STAGE stays below
    }

    // epilogue: + bias, convert bf16, store
    float bv[4];
    #pragma unroll
    for (int ni = 0; ni < 4; ++ni)
        bv[ni] = bias[wn * 64 + ni * 16 + lr];

    u16* gout = gates16 + (size_t)gsel * BF_ELEMS;
    #pragma unroll
    for (int mi = 0; mi < 4; ++mi)
        #pragma unroll
        for (int ni = 0; ni < 4; ++ni)
            #pragma unroll
            for (int r = 0; r < 4; ++r) {
                int row = row0 + wm * 64 + mi * 16 + lk * 4 + r;
                int col = hd * 256 + e0 + wn * 64 + ni * 16 + lr;
                gout[row * 1024 + col] = f2bf(acc[mi][ni][r] + bv[ni]);
            }
    #undef STAGE_TILE
}

// pointwise gate math + per-head LayerNorm; one block per row, one wave per head
__global__ __launch_bounds__(256) void kpoint(
    const u16* __restrict__ gates16,
    const float* __restrict__ c, const float* __restrict__ n, const float* __restrict__ m,
    const float* __restrict__ ln_scale, const int* __restrict__ flagp,
    float* __restrict__ out) {
    int b = blockIdx.x;
    int t = threadIdx.x;
    int l = t & 63;
    int j = (t >> 6) * 256 + l * 4;
    int idx = b * 1024 + j;
    int flag = *flagp;

    u16x4 iv = *(const u16x4*)(gates16 + idx);
    u16x4 fv = *(const u16x4*)(gates16 + (size_t)BF_ELEMS + idx);
    u16x4 zv = *(const u16x4*)(gates16 + 2 * (size_t)BF_ELEMS + idx);
    u16x4 ov = *(const u16x4*)(gates16 + 3 * (size_t)BF_ELEMS + idx);
    f32x4 cv = *(const f32x4*)(c + idx);
    f32x4 nv = *(const f32x4*)(n + idx);
    f32x4 mv = *(const f32x4*)(m + idx);
    f32x4 sc = *(const f32x4*)(ln_scale + j);

    f32x4 cn, nn, mn, hn;
    float s = 0.f, ss = 0.f;
    #pragma unroll
    for (int q = 0; q < 4; ++q) {
        float I = bf2f(iv[q]);
        float Fg = bf2f(fv[q]);
        float Z = bf2f(zv[q]);
        float O = bf2f(ov[q]);
        float og = 1.f / (1.f + expf(-O));
        float lf = (Fg >= 0.f) ? -log1pf(expf(-Fg)) : (Fg - log1pf(expf(Fg)));
        float mnew = flag ? fmaxf(lf + mv[q], I) : I;
        float ip = fminf(expf(I - mnew), 1.f);
        float fp = fminf(expf(lf + mv[q] - mnew), 1.f);
        float cnew = fp * cv[q] + ip * tanhf(Z);
        float nnew = fp * nv[q] + ip;
        float hnew = og * (cnew / fmaxf(nnew, 1e-6f));
        cn[q] = cnew; nn[q] = nnew; mn[q] = mnew; hn[q] = hnew;
        s += hnew; ss += hnew * hnew;
    }
    #pragma unroll
    for (int off = 32; off >= 1; off >>= 1) {
        s  += __shfl_xor(s, off);
        ss += __shfl_xor(ss, off);
    }
    float mu = s * (1.f / 256.f);
    float var = ss * (1.f / 256.f) - mu * mu;
    float rs = rsqrtf(var + 1e-6f);

    f32x4 o4;
    #pragma unroll
    for (int q = 0; q < 4; ++q)
        o4[q] = (hn[q] - mu) * rs * sc[q];

    *(f32x4*)(out + idx) = o4;
    *(f32x4*)(out + (size_t)BF_ELEMS + idx) = cn;
    *(f32x4*)(out + 2 * (size_t)BF_ELEMS + idx) = nn;
    *(f32x4*)(out + 3 * (size_t)BF_ELEMS + idx) = mn;
    *(f32x4*)(out + 4 * (size_t)BF_ELEMS + idx) = hn;
}

extern "C" void kernel_launch(void* const* d_in, const int* in_sizes, int n_in,
                              void* d_out, int out_size, void* d_ws, size_t ws_size,
                              hipStream_t stream) {
    const float* inputs = (const float*)d_in[0];
    const float* c = (const float*)d_in[1];
    const float* n = (const float*)d_in[2];
    const float* m = (const float*)d_in[3];
    const float* h = (const float*)d_in[4];
    const float* conv_state = (const float*)d_in[5];
    const float* conv_kernel = (const float*)d_in[6];
    const float* conv_bias = (const float*)d_in[7];
    const float* W[8];
    for (int i = 0; i < 8; ++i) W[i] = (const float*)d_in[8 + i];
    const float* bgi = (const float*)d_in[16];
    const float* bgf = (const float*)d_in[17];
    const float* bgz = (const float*)d_in[18];
    const float* bgo = (const float*)d_in[19];
    const float* ln_scale = (const float*)d_in[20];
    float* out = (float*)d_out;

    char* ws = (char*)d_ws;
    int* flag = (int*)ws;
    u16* convact = (u16*)(ws + 256);
    u16* hbf = convact + BF_ELEMS;
    u16* inbf = hbf + BF_ELEMS;
    u16* wt = inbf + BF_ELEMS;                       // 8*4*65536 bf16
    u16* gates16 = wt + (size_t)8 * 4 * 65536;       // 4 * BF_ELEMS bf16

    hipMemsetAsync(flag, 0, 4, stream);
    kprep<<<6144, 256, 0, stream>>>(inputs, conv_state, conv_kernel, conv_bias, h, n,
                                    W[0], W[1], W[2], W[3], W[4], W[5], W[6], W[7],
                                    out + 5 * (size_t)BF_ELEMS, convact, hbf, inbf, wt, flag);
    kgemm<<<dim3(32, 32), 256, 0, stream>>>(convact, inbf, hbf, wt,
                                            bgi, bgf, bgz, bgo, gates16);
    kpoint<<<4096, 256, 0, stream>>>(gates16, c, n, m, ln_scale, flag, out);
}